// Round 7
// baseline (3075.670 us; speedup 1.0000x reference)
//
#include <hip/hip_runtime.h>
#include <math.h>

// ---------------------------------------------------------------------------
// STAttentionRecBlock, sample-chunked (G samples/pass, G from ws_size).
// 8 logical samples: 0..3 = x, 4..7 = x1. Output flat: sample ns at ns*SAMP.
// R7:  gemm_conv family -> bf16x3 MFMA, 3233->2677us.
// R8:  apply_t -> bf16x3 MFMA, 2677->2284us.
// R9:  scores_t -> bf16x3 MFMA + fused tanh finalize, 2284->2031us.
// R10: compact blocked LDS (LIDX), conflicts 5.8M->1.9M, LDS 32KB. Neutral:
//      occupancy stayed 21%, dur flat -> latency-bound confirmed by pipes
//      (Mfma 8%, VALU 14%, HBM 21%): vmcnt(0)-before-LDS-write exposes ~900cy
//      HBM latency against a ~400cy MFMA window.
// R11: (a) double-buffered LDS (2x32KB), ONE barrier/k-step (write->bar->mfma);
//      (b) two-deep register staging: loads for k+32 issued at phase top,
//          giving a full-iteration load window;
//      (c) grid transposed so m-tiles are consecutive -> B panel L2-reused
//          (FETCH 256MB -> ~110MB expected on in-gemm);
//      (d) apply_t K padded 416->448 (multiple of 64).
// Workspace per chunk-sample: A 3.84M f | Zs 2.56M f | aT 0.48M f | sp 15000
//   | as 1875 = 27,587,500 B per G. G adaptive in {8,4,2,1}.
// ---------------------------------------------------------------------------

#define PP 10000          // T*V
#define SAMP 2560000      // C*PP

typedef __attribute__((ext_vector_type(8))) __bf16 bf16x8;
typedef __attribute__((ext_vector_type(4))) float f32x4;

// blocked LDS index: k-group g (8 bf16 each), row r (0..127); 16B units.
#define LIDX(g, r) ((g) * 128 + ((r) ^ (g)))

__device__ __forceinline__ float4 ld4(const float* p) { return *(const float4*)p; }
__device__ __forceinline__ float lrelu(float v) { return v >= 0.f ? v : 0.1f * v; }

// ---------------------------------------------------------------------------
// bf16x3 MFMA conv-as-GEMM. blockIdx.z = ln (chunk-local sample).
// m0 from blockIdx.x (fastest -> consecutive blocks share B panel via L2),
// p0 from blockIdx.y.
// MODE 0: out = acc + bias
// MODE 1: out = lrelu(res + g*(acc+bias) + beta)            (ff)
// MODE 2: out = acc                                         (out-gemm s=0)
// MODE 3: out += acc                                        (out-gemm s=1)
// MODE 4: out = lrelu(res + g*(out + acc + bias) + beta)    (out-gemm s=2)
// MODE 5: out = acc + bias, written as qkT[sec][t][v*64+cl] (temporal in-gemm)
// Tile: 128m x 128p x 32k. 4 waves (2x2), wave = 64x64 = 4x4 16x16 frags.
// ---------------------------------------------------------------------------
template<int MODE, bool PE, bool BGLOB, bool OUTGLOB>
__global__ __launch_bounds__(256)
void gemm_mfma(const float* __restrict__ W, int Kw,
               const float* __restrict__ bias,
               const float* __restrict__ g, const float* __restrict__ beta,
               const float* __restrict__ bg0, const float* __restrict__ bg1,
               const float* __restrict__ bw,
               const float* __restrict__ pe,
               const float* rg0, const float* rg1,
               float* out, int n0, int M, int K)
{
    const int ln = blockIdx.z;
    const int ns = n0 + ln;
    const int m0 = blockIdx.x * 128;
    const int p0 = blockIdx.y * 128;
    const int tid = threadIdx.x;

    const float* Bp;
    if (BGLOB)
        Bp = (ns < 4) ? bg0 + (size_t)ns * (size_t)K * PP
                      : bg1 + (size_t)(ns - 4) * (size_t)K * PP;
    else
        Bp = bw + (size_t)ln * (size_t)K * PP;

    __shared__ __align__(16) bf16x8 AhL[2][512];
    __shared__ __align__(16) bf16x8 AlL[2][512];
    __shared__ __align__(16) bf16x8 BhL[2][512];
    __shared__ __align__(16) bf16x8 BlL[2][512];

    const int am  = tid >> 1;            // A row 0..127
    const int akb = (tid & 1) * 16;      // A k base 0/16
    const int ag0 = akb >> 3;            // A k-groups ag0, ag0+1
    const float* wrow = W + (size_t)(m0 + am) * Kw + akb;

    const int bp  = tid & 127;           // B row (p) 0..127
    const int bkg = (tid >> 7) * 8;      // B k base 0 or 8 (e adds 16)
    const int bg_ = bkg >> 3;            // B k-groups bg_, bg_+2
    const int gp  = p0 + bp;
    const bool pok = gp < PP;

    const int lane = tid & 63;
    const int wv = tid >> 6;
    const int wr = (wv >> 1) * 64, wc = (wv & 1) * 64;
    const int lr = lane & 15;            // frag row (A: m, B: p)
    const int lg = lane >> 4;            // frag k-group 0..3

    f32x4 acc[4][4];
#pragma unroll
    for (int i = 0; i < 4; i++)
#pragma unroll
        for (int j = 0; j < 4; j++) acc[i][j] = (f32x4){0.f, 0.f, 0.f, 0.f};

    float4 wregA[4], wregB[4];
    float  bregA[2][8], bregB[2][8];

    auto loadW = [&](int kc, float4* wreg) {
#pragma unroll
        for (int q = 0; q < 4; q++) wreg[q] = ld4(wrow + kc + q * 4);
    };
    auto loadBv = [&](int kc, float breg[2][8]) {
#pragma unroll
        for (int e = 0; e < 2; e++) {
            const int kk = kc + bkg + e * 16;
#pragma unroll
            for (int i = 0; i < 8; i++) {
                float v = 0.f;
                if (pok) {
                    v = Bp[(size_t)(kk + i) * PP + gp];
                    if (PE) v += pe[(size_t)(kk + i) * PP + gp];
                }
                breg[e][i] = v;
            }
        }
    };
    auto stageA = [&](const float4* wreg, int buf) {
        bf16x8 h0, h1, l0, l1;
#pragma unroll
        for (int q = 0; q < 4; q++) {
            const float vs0 = wreg[q].x, vs1 = wreg[q].y, vs2 = wreg[q].z, vs3 = wreg[q].w;
            __bf16 hh; const int ib = q * 4;
#define CVTA(c, val) { hh = (__bf16)(val); __bf16 ll = (__bf16)((val) - (float)hh); \
    if (ib + c < 8) { h0[ib + c] = hh; l0[ib + c] = ll; } else { h1[ib + c - 8] = hh; l1[ib + c - 8] = ll; } }
            CVTA(0, vs0) CVTA(1, vs1) CVTA(2, vs2) CVTA(3, vs3)
#undef CVTA
        }
        AhL[buf][LIDX(ag0, am)]     = h0;
        AhL[buf][LIDX(ag0 + 1, am)] = h1;
        AlL[buf][LIDX(ag0, am)]     = l0;
        AlL[buf][LIDX(ag0 + 1, am)] = l1;
    };
    auto stageB = [&](const float breg[2][8], int buf) {
#pragma unroll
        for (int e = 0; e < 2; e++) {
            bf16x8 hb, lb;
#pragma unroll
            for (int i = 0; i < 8; i++) {
                __bf16 hh = (__bf16)breg[e][i];
                hb[i] = hh;
                lb[i] = (__bf16)(breg[e][i] - (float)hh);
            }
            BhL[buf][LIDX(bg_ + 2 * e, bp)] = hb;
            BlL[buf][LIDX(bg_ + 2 * e, bp)] = lb;
        }
    };
    auto domfma = [&](int buf) {
        bf16x8 fbh[4], fbl[4];
#pragma unroll
        for (int fj = 0; fj < 4; fj++) {
            fbh[fj] = BhL[buf][LIDX(lg, wc + fj * 16 + lr)];
            fbl[fj] = BlL[buf][LIDX(lg, wc + fj * 16 + lr)];
        }
#pragma unroll
        for (int fi = 0; fi < 4; fi++) {
            bf16x8 fah = AhL[buf][LIDX(lg, wr + fi * 16 + lr)];
            bf16x8 fal = AlL[buf][LIDX(lg, wr + fi * 16 + lr)];
#pragma unroll
            for (int fj = 0; fj < 4; fj++) {
                acc[fi][fj] = __builtin_amdgcn_mfma_f32_16x16x32_bf16(fah, fbh[fj], acc[fi][fj], 0, 0, 0);
                acc[fi][fj] = __builtin_amdgcn_mfma_f32_16x16x32_bf16(fah, fbl[fj], acc[fi][fj], 0, 0, 0);
                acc[fi][fj] = __builtin_amdgcn_mfma_f32_16x16x32_bf16(fal, fbh[fj], acc[fi][fj], 0, 0, 0);
            }
        }
    };

    // K is a multiple of 64 here (256). Two phases per iteration.
    loadW(0, wregA); loadBv(0, bregA);
    int buf = 0;
    for (int k0 = 0; k0 < K; k0 += 64) {
        // phase 0: issue loads for k0+32 FIRST (full-iteration window)
        if (k0 + 32 < K) { loadW(k0 + 32, wregB); loadBv(k0 + 32, bregB); }
        stageA(wregA, buf); stageB(bregA, buf);
        __syncthreads();
        domfma(buf);
        buf ^= 1;
        // phase 1
        if (k0 + 64 < K) { loadW(k0 + 64, wregA); loadBv(k0 + 64, bregA); }
        stageA(wregB, buf); stageB(bregB, buf);
        __syncthreads();
        domfma(buf);
        buf ^= 1;
    }

    const int rb = (lane >> 4) * 4;      // frag row base (C/D layout)

    if (MODE == 5) {
        // Transposed write: qkT[ln][sec][t][v*64 + cl]; float4 over reg dim.
#pragma unroll
        for (int fi = 0; fi < 4; fi++) {
            const int mb = m0 + wr + fi * 16 + rb;
            const int sec = mb >> 6, cl = mb & 63;
            float* qt = out + (size_t)ln * 3840000ull + (size_t)sec * 640000ull + cl;
            const float b0 = bias[mb], b1 = bias[mb + 1], b2 = bias[mb + 2], b3 = bias[mb + 3];
#pragma unroll
            for (int fj = 0; fj < 4; fj++) {
                const int p = p0 + wc + fj * 16 + lr;
                if (p >= PP) continue;
                const int t = p / 25, v = p - t * 25;
                f32x4 a = acc[fi][fj];
                *(float4*)(qt + (size_t)t * 1600 + v * 64) =
                    make_float4(a[0] + b0, a[1] + b1, a[2] + b2, a[3] + b3);
            }
        }
        return;
    }

    float* op = out + (OUTGLOB ? (size_t)ns : (size_t)ln) * (size_t)M * PP;
    const float* resp = nullptr;
    if (MODE == 1 || MODE == 4)
        resp = (ns < 4) ? rg0 + (size_t)ns * SAMP : rg1 + (size_t)(ns - 4) * SAMP;

#pragma unroll
    for (int fi = 0; fi < 4; fi++) {
#pragma unroll
        for (int r = 0; r < 4; r++) {
            const int m = m0 + wr + fi * 16 + rb + r;
            const float bi = (MODE == 0 || MODE == 1 || MODE == 4) ? bias[m] : 0.f;
            const float gi = (MODE == 1 || MODE == 4) ? g[m] : 0.f;
            const float be = (MODE == 1 || MODE == 4) ? beta[m] : 0.f;
            const size_t rowoff = (size_t)m * PP;
#pragma unroll
            for (int fj = 0; fj < 4; fj++) {
                const int p = p0 + wc + fj * 16 + lr;
                if (p >= PP) continue;
                const float a = acc[fi][fj][r];
                float val;
                if (MODE == 0)      val = a + bi;
                else if (MODE == 2) val = a;
                else if (MODE == 3) val = op[rowoff + p] + a;
                else if (MODE == 4) val = lrelu(resp[rowoff + p] + gi * (op[rowoff + p] + a + bi) + be);
                else                val = lrelu(resp[rowoff + p] + gi * (a + bi) + be);
                op[rowoff + p] = val;
            }
        }
    }
}

// ---------------------------------------------------------------------------
// R8/R11: temporal apply as bf16x3 MFMA. Grid (4, 50, G), one dispatch per s.
// q0 from blockIdx.x (fastest -> Y panel L2-reused), j0 from blockIdx.y.
// z[ln][c][q][v] = sum_t attT[(ln*3+s)][q][t] * Y[ns][c][t][v], K pad 448.
// ---------------------------------------------------------------------------
__global__ __launch_bounds__(256)
void apply_t_mfma(const float* __restrict__ y, const float* __restrict__ attT,
                  float* __restrict__ z, int n0, int s)
{
    const int ln = blockIdx.z;
    const int ns = n0 + ln;
    const int q0 = blockIdx.x * 128;
    const int j0 = blockIdx.y * 128;
    const float* A = attT + ((size_t)ln * 3 + s) * 160000ull;
    const float* Y = y + (size_t)ns * SAMP;
    float* zout = z + (size_t)ln * SAMP;
    const int tid = threadIdx.x;

    __shared__ __align__(16) bf16x8 AhL[2][512];
    __shared__ __align__(16) bf16x8 AlL[2][512];
    __shared__ __align__(16) bf16x8 BhL[2][512];
    __shared__ __align__(16) bf16x8 BlL[2][512];

    const int am  = tid >> 1;
    const int akb = (tid & 1) * 16;
    const int ag0 = akb >> 3;
    const int qA  = q0 + am;
    const float* arow = A + (size_t)qA * 400;

    const int bp  = tid & 127;
    const int bkg = (tid >> 7) * 8;
    const int bg_ = bkg >> 3;
    const int j   = j0 + bp;
    const int cB  = j / 25, vB = j % 25;
    const float* yrow = Y + (size_t)cB * PP + vB;   // + t*25

    const int lane = tid & 63;
    const int wv = tid >> 6;
    const int wr = (wv >> 1) * 64, wc = (wv & 1) * 64;
    const int lr = lane & 15;
    const int lg = lane >> 4;

    f32x4 acc[4][4];
#pragma unroll
    for (int i = 0; i < 4; i++)
#pragma unroll
        for (int jj = 0; jj < 4; jj++) acc[i][jj] = (f32x4){0.f, 0.f, 0.f, 0.f};

    float4 wregA[4], wregB[4];
    float  bregA[2][8], bregB[2][8];

    auto loadW = [&](int kc, float4* wreg) {
#pragma unroll
        for (int q = 0; q < 4; q++) {
            const int ks_ = kc + akb + q * 4;
            float4 v = make_float4(0.f, 0.f, 0.f, 0.f);
            if (qA < 400 && ks_ < 400) v = ld4(arow + ks_);
            wreg[q] = v;
        }
    };
    auto loadBv = [&](int kc, float breg[2][8]) {
#pragma unroll
        for (int e = 0; e < 2; e++) {
            const int kb = kc + bkg + e * 16;
#pragma unroll
            for (int i = 0; i < 8; i++) {
                const int t = kb + i;
                breg[e][i] = (t < 400) ? yrow[(size_t)t * 25] : 0.f;
            }
        }
    };
    auto stageA = [&](const float4* wreg, int buf) {
        bf16x8 h0, h1, l0, l1;
#pragma unroll
        for (int q = 0; q < 4; q++) {
            const float vs0 = wreg[q].x, vs1 = wreg[q].y, vs2 = wreg[q].z, vs3 = wreg[q].w;
            __bf16 hh; const int ib = q * 4;
#define CVTA(c, val) { hh = (__bf16)(val); __bf16 ll = (__bf16)((val) - (float)hh); \
    if (ib + c < 8) { h0[ib + c] = hh; l0[ib + c] = ll; } else { h1[ib + c - 8] = hh; l1[ib + c - 8] = ll; } }
            CVTA(0, vs0) CVTA(1, vs1) CVTA(2, vs2) CVTA(3, vs3)
#undef CVTA
        }
        AhL[buf][LIDX(ag0, am)]     = h0;
        AhL[buf][LIDX(ag0 + 1, am)] = h1;
        AlL[buf][LIDX(ag0, am)]     = l0;
        AlL[buf][LIDX(ag0 + 1, am)] = l1;
    };
    auto stageB = [&](const float breg[2][8], int buf) {
#pragma unroll
        for (int e = 0; e < 2; e++) {
            bf16x8 hb, lb;
#pragma unroll
            for (int i = 0; i < 8; i++) {
                __bf16 hh = (__bf16)breg[e][i];
                hb[i] = hh;
                lb[i] = (__bf16)(breg[e][i] - (float)hh);
            }
            BhL[buf][LIDX(bg_ + 2 * e, bp)] = hb;
            BlL[buf][LIDX(bg_ + 2 * e, bp)] = lb;
        }
    };
    auto domfma = [&](int buf) {
        bf16x8 fbh[4], fbl[4];
#pragma unroll
        for (int fj = 0; fj < 4; fj++) {
            fbh[fj] = BhL[buf][LIDX(lg, wc + fj * 16 + lr)];
            fbl[fj] = BlL[buf][LIDX(lg, wc + fj * 16 + lr)];
        }
#pragma unroll
        for (int fi = 0; fi < 4; fi++) {
            bf16x8 fah = AhL[buf][LIDX(lg, wr + fi * 16 + lr)];
            bf16x8 fal = AlL[buf][LIDX(lg, wr + fi * 16 + lr)];
#pragma unroll
            for (int fj = 0; fj < 4; fj++) {
                acc[fi][fj] = __builtin_amdgcn_mfma_f32_16x16x32_bf16(fah, fbh[fj], acc[fi][fj], 0, 0, 0);
                acc[fi][fj] = __builtin_amdgcn_mfma_f32_16x16x32_bf16(fah, fbl[fj], acc[fi][fj], 0, 0, 0);
                acc[fi][fj] = __builtin_amdgcn_mfma_f32_16x16x32_bf16(fal, fbh[fj], acc[fi][fj], 0, 0, 0);
            }
        }
    };

    // K padded to 448 (7 x 64); loads internally guarded at t<400.
    loadW(0, wregA); loadBv(0, bregA);
    int buf = 0;
    for (int k0 = 0; k0 < 448; k0 += 64) {
        if (k0 + 32 < 448) { loadW(k0 + 32, wregB); loadBv(k0 + 32, bregB); }
        stageA(wregA, buf); stageB(bregA, buf);
        __syncthreads();
        domfma(buf);
        buf ^= 1;
        if (k0 + 64 < 448) { loadW(k0 + 64, wregA); loadBv(k0 + 64, bregA); }
        stageA(wregB, buf); stageB(bregB, buf);
        __syncthreads();
        domfma(buf);
        buf ^= 1;
    }

    const int rb = (lane >> 4) * 4;
#pragma unroll
    for (int fi = 0; fi < 4; fi++) {
#pragma unroll
        for (int r = 0; r < 4; r++) {
            const int q = q0 + wr + fi * 16 + rb + r;
            if (q >= 400) continue;
#pragma unroll
            for (int fj = 0; fj < 4; fj++) {
                const int p = j0 + wc + fj * 16 + lr;
                const int c = p / 25, v = p - c * 25;
                zout[(size_t)c * PP + (size_t)q * 25 + v] = acc[fi][fj][r];
            }
        }
    }
}

// ---------------------------------------------------------------------------
// R9/R11: temporal scores as bf16x3 MFMA with fused finalize.
// aT[idx][q][t] = tanh(sum_k Aq[q][k]*Bt[t][k] / 1600)*alphat[s] + att0t[s][t][q]
// Grid (16, 3*G): blockIdx.x = qtile*4 + ttile; M/N guarded at 400. K=1600.
// ---------------------------------------------------------------------------
__global__ __launch_bounds__(256)
void scores_t_mfma(const float* __restrict__ qkT,
                   const float* __restrict__ alphat,
                   const float* __restrict__ att0t,
                   float* __restrict__ aT)
{
    const int idx = blockIdx.y;          // ln*3 + s
    const int s = idx % 3, ln = idx / 3;
    const int t0 = (blockIdx.x & 3) * 128;
    const int q0 = (blockIdx.x >> 2) * 128;
    const float* base = qkT + (size_t)ln * 3840000ull;
    const float* Aq = base + (size_t)(3 + s) * 640000ull;
    const float* Bt = base + (size_t)s * 640000ull;
    const int tid = threadIdx.x;

    __shared__ __align__(16) bf16x8 AhL[2][512];
    __shared__ __align__(16) bf16x8 AlL[2][512];
    __shared__ __align__(16) bf16x8 BhL[2][512];
    __shared__ __align__(16) bf16x8 BlL[2][512];

    const int am  = tid >> 1;
    const int akb = (tid & 1) * 16;
    const int ag0 = akb >> 3;
    const int qA  = q0 + am;
    const int tB  = t0 + am;
    const float* arow = Aq + (size_t)qA * 1600 + akb;
    const float* brow = Bt + (size_t)tB * 1600 + akb;
    const bool aok = qA < 400;
    const bool bok = tB < 400;

    const int lane = tid & 63;
    const int wv = tid >> 6;
    const int wr = (wv >> 1) * 64, wc = (wv & 1) * 64;
    const int lr = lane & 15;
    const int lg = lane >> 4;

    f32x4 acc[4][4];
#pragma unroll
    for (int i = 0; i < 4; i++)
#pragma unroll
        for (int j = 0; j < 4; j++) acc[i][j] = (f32x4){0.f, 0.f, 0.f, 0.f};

    float4 aregA[4], brgA[4], aregB[4], brgB[4];

    auto loadAB = [&](int kc, float4* areg, float4* brg) {
#pragma unroll
        for (int q = 0; q < 4; q++) {
            areg[q] = aok ? ld4(arow + kc + q * 4) : make_float4(0.f, 0.f, 0.f, 0.f);
            brg[q]  = bok ? ld4(brow + kc + q * 4) : make_float4(0.f, 0.f, 0.f, 0.f);
        }
    };
    auto stageAB = [&](const float4* areg, const float4* brg, int buf) {
        {
            bf16x8 h0, h1, l0, l1;
#pragma unroll
            for (int q = 0; q < 4; q++) {
                const float vs0 = areg[q].x, vs1 = areg[q].y, vs2 = areg[q].z, vs3 = areg[q].w;
                __bf16 hh; const int ib = q * 4;
#define CVTA(c, val) { hh = (__bf16)(val); __bf16 ll = (__bf16)((val) - (float)hh); \
    if (ib + c < 8) { h0[ib + c] = hh; l0[ib + c] = ll; } else { h1[ib + c - 8] = hh; l1[ib + c - 8] = ll; } }
                CVTA(0, vs0) CVTA(1, vs1) CVTA(2, vs2) CVTA(3, vs3)
#undef CVTA
            }
            AhL[buf][LIDX(ag0, am)]     = h0;
            AhL[buf][LIDX(ag0 + 1, am)] = h1;
            AlL[buf][LIDX(ag0, am)]     = l0;
            AlL[buf][LIDX(ag0 + 1, am)] = l1;
        }
        {
            bf16x8 h0, h1, l0, l1;
#pragma unroll
            for (int q = 0; q < 4; q++) {
                const float vs0 = brg[q].x, vs1 = brg[q].y, vs2 = brg[q].z, vs3 = brg[q].w;
                __bf16 hh; const int ib = q * 4;
#define CVTB(c, val) { hh = (__bf16)(val); __bf16 ll = (__bf16)((val) - (float)hh); \
    if (ib + c < 8) { h0[ib + c] = hh; l0[ib + c] = ll; } else { h1[ib + c - 8] = hh; l1[ib + c - 8] = ll; } }
                CVTB(0, vs0) CVTB(1, vs1) CVTB(2, vs2) CVTB(3, vs3)
#undef CVTB
            }
            BhL[buf][LIDX(ag0, am)]     = h0;
            BhL[buf][LIDX(ag0 + 1, am)] = h1;
            BlL[buf][LIDX(ag0, am)]     = l0;
            BlL[buf][LIDX(ag0 + 1, am)] = l1;
        }
    };
    auto domfma = [&](int buf) {
        bf16x8 fbh[4], fbl[4];
#pragma unroll
        for (int fj = 0; fj < 4; fj++) {
            fbh[fj] = BhL[buf][LIDX(lg, wc + fj * 16 + lr)];
            fbl[fj] = BlL[buf][LIDX(lg, wc + fj * 16 + lr)];
        }
#pragma unroll
        for (int fi = 0; fi < 4; fi++) {
            bf16x8 fah = AhL[buf][LIDX(lg, wr + fi * 16 + lr)];
            bf16x8 fal = AlL[buf][LIDX(lg, wr + fi * 16 + lr)];
#pragma unroll
            for (int fj = 0; fj < 4; fj++) {
                acc[fi][fj] = __builtin_amdgcn_mfma_f32_16x16x32_bf16(fah, fbh[fj], acc[fi][fj], 0, 0, 0);
                acc[fi][fj] = __builtin_amdgcn_mfma_f32_16x16x32_bf16(fah, fbl[fj], acc[fi][fj], 0, 0, 0);
                acc[fi][fj] = __builtin_amdgcn_mfma_f32_16x16x32_bf16(fal, fbh[fj], acc[fi][fj], 0, 0, 0);
            }
        }
    };

    loadAB(0, aregA, brgA);
    int buf = 0;
    for (int k0 = 0; k0 < 1600; k0 += 64) {
        if (k0 + 32 < 1600) loadAB(k0 + 32, aregB, brgB);
        stageAB(aregA, brgA, buf);
        __syncthreads();
        domfma(buf);
        buf ^= 1;
        if (k0 + 64 < 1600) loadAB(k0 + 64, aregA, brgA);
        stageAB(aregB, brgB, buf);
        __syncthreads();
        domfma(buf);
        buf ^= 1;
    }

    const int rb = (lane >> 4) * 4;
    const float al = alphat[s];
    float* aTp = aT + (size_t)idx * 160000ull;
    const float* a0p = att0t + (size_t)s * 160000ull;

#pragma unroll
    for (int fi = 0; fi < 4; fi++) {
        const int qb = q0 + wr + fi * 16 + rb;
#pragma unroll
        for (int fj = 0; fj < 4; fj++) {
            const int t = t0 + wc + fj * 16 + lr;
            if (t >= 400) continue;
#pragma unroll
            for (int r = 0; r < 4; r++) {
                const int q = qb + r;
                if (q >= 400) continue;
                aTp[(size_t)q * 400 + t] =
                    tanhf(acc[fi][fj][r] * (1.f / 1600.f)) * al + a0p[(size_t)t * 400 + q];
            }
        }
    }
}

// ---------------------------------------------------------------------------
// Spatial scores, partial K: 200 chunks of 128 rows. Grid (200, 3, G).  [R0]
// ---------------------------------------------------------------------------
__global__ __launch_bounds__(256)
void scores_s_partial(const float* __restrict__ qk, float* __restrict__ part)
{
    const int chunk = blockIdx.x, s = blockIdx.y, ln = blockIdx.z;
    const float* qsec = qk + ((size_t)ln * 384 + s * 64) * PP + (size_t)chunk * 3200;
    const float* ksec = qk + ((size_t)ln * 384 + (3 + s) * 64) * PP + (size_t)chunk * 3200;
    __shared__ float QL[3200];
    __shared__ float KL[3200];
    const int tid = threadIdx.x;
    for (int i = tid; i < 3200; i += 256) {
        QL[i] = qsec[i];
        KL[i] = ksec[i];
    }
    __syncthreads();
    const int o0 = tid, o1 = tid + 256, o2 = tid + 512;
    const int u0 = o0 / 25, v0 = o0 % 25;
    const int u1 = o1 / 25, v1 = o1 % 25;
    const int u2 = o2 / 25, v2 = o2 % 25;
    float a0 = 0.f, a1 = 0.f, a2 = 0.f;
#pragma unroll 8
    for (int r = 0; r < 128; r++) {
        int ro = r * 25;
        a0 = fmaf(QL[ro + u0], KL[ro + v0], a0);
        a1 = fmaf(QL[ro + u1], KL[ro + v1], a1);
        if (tid < 113) a2 = fmaf(QL[ro + u2], KL[ro + v2], a2);
    }
    float* pp = part + (((size_t)(ln * 3 + s)) * 200 + chunk) * 625;
    pp[o0] = a0;
    pp[o1] = a1;
    if (tid < 113) pp[o2] = a2;
}

// grid.x = 3*G blocks (idx = ln*3+s), 640 threads. Sums 200 partials.  [R0]
__global__ void scores_s_final(const float* __restrict__ part,
                               const float* __restrict__ alphas,
                               const float* __restrict__ att0s,
                               float* __restrict__ atts)
{
    const int idx = blockIdx.x;
    const int s = idx % 3;
    const int o = threadIdx.x;
    if (o >= 625) return;
    const float* pb = part + (size_t)idx * 200 * 625 + o;
    float sum = 0.f;
#pragma unroll 8
    for (int i = 0; i < 200; i++) sum += pb[(size_t)i * 625];
    atts[(size_t)idx * 625 + o] = tanhf(sum * (1.f / 25600.f)) * alphas[s] + att0s[s * 625 + o];
}

// ---------------------------------------------------------------------------
// Spatial apply (one s). Grid (200, G).  [R0]
// ---------------------------------------------------------------------------
__global__ __launch_bounds__(256)
void apply_s_kernel(const float* __restrict__ x0, const float* __restrict__ x1,
                    const float* __restrict__ atts, float* __restrict__ z,
                    int n0, int s)
{
    const int ln = blockIdx.y;
    const int ns = n0 + ln;
    const int tid = threadIdx.x;
    __shared__ float attL[700];   // 25*28 padded
    for (int i = tid; i < 700; i += 256) attL[i] = 0.f;
    __syncthreads();
    for (int i = tid; i < 625; i += 256) {
        int v = i / 25, w = i % 25;
        attL[v * 28 + w] = atts[(size_t)ln * 1875 + s * 625 + i];
    }
    __syncthreads();
    const float* xp = (ns < 4) ? x0 + (size_t)ns * SAMP : x1 + (size_t)(ns - 4) * SAMP;
    const int r0 = (blockIdx.x * 256 + tid) * 2;   // even; both rows share c
    const float* xr0 = xp + (size_t)r0 * 25;
    float xr[2][25];
#pragma unroll
    for (int i = 0; i < 2; i++)
#pragma unroll
        for (int v = 0; v < 25; v++) xr[i][v] = xr0[i * 25 + v];
    const int c0 = r0 / 400, t0 = r0 % 400;

    float4 acc0[7], acc1[7];
#pragma unroll
    for (int w4 = 0; w4 < 7; w4++) {
        acc0[w4] = make_float4(0.f, 0.f, 0.f, 0.f);
        acc1[w4] = make_float4(0.f, 0.f, 0.f, 0.f);
    }
#pragma unroll
    for (int v = 0; v < 25; v++) {
        const float4* arow = (const float4*)&attL[v * 28];
        float xv0 = xr[0][v], xv1 = xr[1][v];
#pragma unroll
        for (int w4 = 0; w4 < 7; w4++) {
            float4 a = arow[w4];
            acc0[w4].x = fmaf(xv0, a.x, acc0[w4].x);
            acc0[w4].y = fmaf(xv0, a.y, acc0[w4].y);
            acc0[w4].z = fmaf(xv0, a.z, acc0[w4].z);
            acc0[w4].w = fmaf(xv0, a.w, acc0[w4].w);
            acc1[w4].x = fmaf(xv1, a.x, acc1[w4].x);
            acc1[w4].y = fmaf(xv1, a.y, acc1[w4].y);
            acc1[w4].z = fmaf(xv1, a.z, acc1[w4].z);
            acc1[w4].w = fmaf(xv1, a.w, acc1[w4].w);
        }
    }
    float* zp = z + (size_t)ln * SAMP + (size_t)c0 * PP + (size_t)t0 * 25;
#pragma unroll
    for (int w4 = 0; w4 < 7; w4++) {
        int wb = w4 * 4;
        if (wb + 0 < 25) zp[wb + 0] = acc0[w4].x;
        if (wb + 1 < 25) zp[wb + 1] = acc0[w4].y;
        if (wb + 2 < 25) zp[wb + 2] = acc0[w4].z;
        if (wb + 3 < 25) zp[wb + 3] = acc0[w4].w;
    }
#pragma unroll
    for (int w4 = 0; w4 < 7; w4++) {
        int wb = w4 * 4;
        if (wb + 0 < 25) zp[25 + wb + 0] = acc1[w4].x;
        if (wb + 1 < 25) zp[25 + wb + 1] = acc1[w4].y;
        if (wb + 2 < 25) zp[25 + wb + 2] = acc1[w4].z;
        if (wb + 3 < 25) zp[25 + wb + 3] = acc1[w4].w;
    }
}

// ---------------------------------------------------------------------------
extern "C" void kernel_launch(void* const* d_in, const int* in_sizes, int n_in,
                              void* d_out, int out_size, void* d_ws, size_t ws_size,
                              hipStream_t stream)
{
    const float* x    = (const float*)d_in[0];
    const float* x1   = (const float*)d_in[1];
    const float* pe_s = (const float*)d_in[2];
    const float* pe_t = (const float*)d_in[3];
    const float* Wsi  = (const float*)d_in[4];
    const float* bsi  = (const float*)d_in[5];
    const float* alphas = (const float*)d_in[6];
    const float* att0s  = (const float*)d_in[7];
    const float* Wso  = (const float*)d_in[8];
    const float* bso  = (const float*)d_in[9];
    const float* gso  = (const float*)d_in[10];
    const float* beso = (const float*)d_in[11];
    const float* Wsf  = (const float*)d_in[12];
    const float* bsf  = (const float*)d_in[13];
    const float* gsf  = (const float*)d_in[14];
    const float* besf = (const float*)d_in[15];
    const float* Wti  = (const float*)d_in[16];
    const float* bti  = (const float*)d_in[17];
    const float* alphat = (const float*)d_in[18];
    const float* att0t  = (const float*)d_in[19];
    const float* Wto  = (const float*)d_in[20];
    const float* bto  = (const float*)d_in[21];
    const float* gto  = (const float*)d_in[22];
    const float* beto = (const float*)d_in[23];
    const float* Wtf  = (const float*)d_in[24];
    const float* btf  = (const float*)d_in[25];
    const float* gtf  = (const float*)d_in[26];
    const float* betf = (const float*)d_in[27];

    float* outp = (float*)d_out;
    const float* outpB = outp + 4ull * SAMP;   // samples 4..7 view

    int G = 1;
    for (int g = 8; g >= 1; g >>= 1) {
        if ((size_t)g * 27587500ull <= ws_size) { G = g; break; }
    }

    float* A   = (float*)d_ws;                       // qk / qkT, then h overlay
    float* Zs  = A  + (size_t)G * 3840000ull;        // z slice / score partials
    float* aT  = Zs + (size_t)G * 2560000ull;        // temporal att
    float* sp  = aT + (size_t)G * 480000ull;         // (unused, kept for layout)
    float* as  = sp + (size_t)G * 15000ull;          // spatial att

    dim3 blk(256);
    for (int n0 = 0; n0 < 8; n0 += G) {
        // grid transposed (R11c): x = m-tile (fastest), y = p-tile.
        dim3 gIn(3, 79, G), gOut(2, 79, G);

        // ---- spatial stage (input x / x1) ----
        gemm_mfma<0, true, true, false><<<gIn, blk, 0, stream>>>(
            Wsi, 256, bsi, nullptr, nullptr, x, x1, nullptr, pe_s,
            nullptr, nullptr, A, n0, 384, 256);
        scores_s_partial<<<dim3(200, 3, G), blk, 0, stream>>>(A, Zs);
        scores_s_final<<<dim3(3 * G), dim3(640), 0, stream>>>(Zs, alphas, att0s, as);
        for (int s = 0; s < 3; s++) {
            apply_s_kernel<<<dim3(200, G), blk, 0, stream>>>(x, x1, as, Zs, n0, s);
            if (s == 0)
                gemm_mfma<2, false, false, false><<<gOut, blk, 0, stream>>>(
                    Wso + s * 256, 768, nullptr, nullptr, nullptr, nullptr, nullptr, Zs,
                    nullptr, nullptr, nullptr, A, n0, 256, 256);
            else if (s == 1)
                gemm_mfma<3, false, false, false><<<gOut, blk, 0, stream>>>(
                    Wso + s * 256, 768, nullptr, nullptr, nullptr, nullptr, nullptr, Zs,
                    nullptr, nullptr, nullptr, A, n0, 256, 256);
            else
                gemm_mfma<4, false, false, false><<<gOut, blk, 0, stream>>>(
                    Wso + s * 256, 768, bso, gso, beso, nullptr, nullptr, Zs,
                    nullptr, x, x1, A, n0, 256, 256);
        }
        gemm_mfma<1, false, false, true><<<gOut, blk, 0, stream>>>(
            Wsf, 256, bsf, gsf, besf, nullptr, nullptr, A, nullptr,
            x, x1, outp, n0, 256, 256);

        // ---- temporal stage (input d_out, in place) ----
        gemm_mfma<5, true, true, false><<<gIn, blk, 0, stream>>>(
            Wti, 256, bti, nullptr, nullptr, outp, outpB, nullptr, pe_t,
            nullptr, nullptr, A, n0, 384, 256);
        scores_t_mfma<<<dim3(16, 3 * G), blk, 0, stream>>>(A, alphat, att0t, aT);
        for (int s = 0; s < 3; s++) {
            apply_t_mfma<<<dim3(4, 50, G), blk, 0, stream>>>(outp, aT, Zs, n0, s);
            if (s == 0)
                gemm_mfma<2, false, false, false><<<gOut, blk, 0, stream>>>(
                    Wto + s * 256, 768, nullptr, nullptr, nullptr, nullptr, nullptr, Zs,
                    nullptr, nullptr, nullptr, A, n0, 256, 256);
            else if (s == 1)
                gemm_mfma<3, false, false, false><<<gOut, blk, 0, stream>>>(
                    Wto + s * 256, 768, nullptr, nullptr, nullptr, nullptr, nullptr, Zs,
                    nullptr, nullptr, nullptr, A, n0, 256, 256);
            else
                gemm_mfma<4, false, false, false><<<gOut, blk, 0, stream>>>(
                    Wto + s * 256, 768, bto, gto, beto, nullptr, nullptr, Zs,
                    nullptr, outp, outpB, A, n0, 256, 256);
        }
        gemm_mfma<1, false, false, true><<<gOut, blk, 0, stream>>>(
            Wtf, 256, btf, gtf, betf, nullptr, nullptr, A, nullptr,
            outp, outpB, outp, n0, 256, 256);
    }
}

// Round 8
// 1812.294 us; speedup vs baseline: 1.6971x; 1.6971x over previous
//
#include <hip/hip_runtime.h>
#include <math.h>

// ---------------------------------------------------------------------------
// STAttentionRecBlock, sample-chunked (G samples/pass, G from ws_size).
// 8 logical samples: 0..3 = x, 4..7 = x1. Output flat: sample ns at ns*SAMP.
// R7:  gemm family -> bf16x3 MFMA, 3233->2677us.
// R8:  apply_t -> bf16x3 MFMA, 2677->2284us.
// R9:  scores_t -> bf16x3 MFMA + fused tanh finalize, 2284->2031us (best).
// R10/R11: LDS relayout / dbuf+2-deep prefetch: neutral/regression. Counters
//      showed occupancy pinned at 21% regardless of LDS: VGPR_Count excludes
//      the 64-AGPR acc[4][4]; 88+64=152 > 128 reg quantum => 2 waves/SIMD.
// R12: re-tile 128m x 64p (wave 64x32, acc[4][2]=32 AGPR) so total regs
//      <= 128 => 4 waves/SIMD (2x residency for the latency-bound loop).
//      LDS 24KB. Same R9 loop structure, grids doubled in p dimension.
// Workspace per chunk-sample: A 3.84M f | Zs 2.56M f | aT 0.48M f | sp 15000
//   | as 1875 = 27,587,500 B per G. G adaptive in {8,4,2,1}.
// ---------------------------------------------------------------------------

#define PP 10000          // T*V
#define SAMP 2560000      // C*PP

typedef __attribute__((ext_vector_type(8))) __bf16 bf16x8;
typedef __attribute__((ext_vector_type(4))) float f32x4;

// blocked LDS index (16B units): A has 128 rows, B has 64 rows.
#define LIDX(g, r)  ((g) * 128 + ((r) ^ (g)))
#define LIDXB(g, r) ((g) * 64 + ((r) ^ (g)))

__device__ __forceinline__ float4 ld4(const float* p) { return *(const float4*)p; }
__device__ __forceinline__ float lrelu(float v) { return v >= 0.f ? v : 0.1f * v; }

// ---------------------------------------------------------------------------
// bf16x3 MFMA conv-as-GEMM. blockIdx.z = ln. Tile 128m x 64p x 32k.
// 4 waves (2x2), wave = 64m x 32p = 4x2 16x16 frags (acc 32 AGPR).
// MODE 0: out = acc + bias
// MODE 1: out = lrelu(res + g*(acc+bias) + beta)            (ff)
// MODE 2: out = acc                                         (out-gemm s=0)
// MODE 3: out += acc                                        (out-gemm s=1)
// MODE 4: out = lrelu(res + g*(out + acc + bias) + beta)    (out-gemm s=2)
// MODE 5: out = acc + bias, written as qkT[sec][t][v*64+cl] (temporal in-gemm)
// ---------------------------------------------------------------------------
template<int MODE, bool PE, bool BGLOB, bool OUTGLOB>
__global__ __launch_bounds__(256)
void gemm_mfma(const float* __restrict__ W, int Kw,
               const float* __restrict__ bias,
               const float* __restrict__ g, const float* __restrict__ beta,
               const float* __restrict__ bg0, const float* __restrict__ bg1,
               const float* __restrict__ bw,
               const float* __restrict__ pe,
               const float* rg0, const float* rg1,
               float* out, int n0, int M, int K)
{
    const int ln = blockIdx.z;
    const int ns = n0 + ln;
    const int p0 = blockIdx.x * 64;
    const int m0 = blockIdx.y * 128;
    const int tid = threadIdx.x;

    const float* Bp;
    if (BGLOB)
        Bp = (ns < 4) ? bg0 + (size_t)ns * (size_t)K * PP
                      : bg1 + (size_t)(ns - 4) * (size_t)K * PP;
    else
        Bp = bw + (size_t)ln * (size_t)K * PP;

    __shared__ __align__(16) bf16x8 AhL[512];   // 4 kgrp x 128 rows
    __shared__ __align__(16) bf16x8 AlL[512];
    __shared__ __align__(16) bf16x8 BhL[256];   // 4 kgrp x 64 rows
    __shared__ __align__(16) bf16x8 BlL[256];

    // A staging: 128 rows x 32 k by 256 threads (16 floats each).
    const int am  = tid >> 1;
    const int akb = (tid & 1) * 16;
    const int ag0 = akb >> 3;                  // 0 or 2
    const float* wrow = W + (size_t)(m0 + am) * Kw + akb;

    // B staging: 64 rows (p) x 32 k by 256 threads (8 floats each).
    const int bp  = tid & 63;
    const int bg_ = tid >> 6;                  // k-group 0..3
    const int bkg = bg_ * 8;
    const int gp  = p0 + bp;
    const bool pok = gp < PP;

    const int lane = tid & 63;
    const int wv = tid >> 6;
    const int wr = (wv >> 1) * 64, wc = (wv & 1) * 32;
    const int lr = lane & 15;
    const int lg = lane >> 4;

    f32x4 acc[4][2];
#pragma unroll
    for (int i = 0; i < 4; i++)
#pragma unroll
        for (int j = 0; j < 2; j++) acc[i][j] = (f32x4){0.f, 0.f, 0.f, 0.f};

    float4 wreg[4];
    float  breg[8];

    auto loadAB = [&](int kc) {
#pragma unroll
        for (int q = 0; q < 4; q++) wreg[q] = ld4(wrow + kc + q * 4);
        const int kk = kc + bkg;
#pragma unroll
        for (int i = 0; i < 8; i++) {
            float v = 0.f;
            if (pok) {
                v = Bp[(size_t)(kk + i) * PP + gp];
                if (PE) v += pe[(size_t)(kk + i) * PP + gp];
            }
            breg[i] = v;
        }
    };

    loadAB(0);

    for (int k0 = 0; k0 < K; k0 += 32) {
        {
            bf16x8 h0, h1, l0, l1;
#pragma unroll
            for (int q = 0; q < 4; q++) {
                const float vs0 = wreg[q].x, vs1 = wreg[q].y, vs2 = wreg[q].z, vs3 = wreg[q].w;
                __bf16 hh; const int ib = q * 4;
#define CVTA(c, val) { hh = (__bf16)(val); __bf16 ll = (__bf16)((val) - (float)hh); \
    if (ib + c < 8) { h0[ib + c] = hh; l0[ib + c] = ll; } else { h1[ib + c - 8] = hh; l1[ib + c - 8] = ll; } }
                CVTA(0, vs0) CVTA(1, vs1) CVTA(2, vs2) CVTA(3, vs3)
#undef CVTA
            }
            AhL[LIDX(ag0, am)]     = h0;
            AhL[LIDX(ag0 + 1, am)] = h1;
            AlL[LIDX(ag0, am)]     = l0;
            AlL[LIDX(ag0 + 1, am)] = l1;
        }
        {
            bf16x8 hb, lb;
#pragma unroll
            for (int i = 0; i < 8; i++) {
                __bf16 hh = (__bf16)breg[i];
                hb[i] = hh;
                lb[i] = (__bf16)(breg[i] - (float)hh);
            }
            BhL[LIDXB(bg_, bp)] = hb;
            BlL[LIDXB(bg_, bp)] = lb;
        }
        __syncthreads();

        const int kn = k0 + 32;
        if (kn < K) loadAB(kn);   // issue next chunk's loads under the MFMAs

        bf16x8 fbh[2], fbl[2];
#pragma unroll
        for (int fj = 0; fj < 2; fj++) {
            fbh[fj] = BhL[LIDXB(lg, wc + fj * 16 + lr)];
            fbl[fj] = BlL[LIDXB(lg, wc + fj * 16 + lr)];
        }
#pragma unroll
        for (int fi = 0; fi < 4; fi++) {
            bf16x8 fah = AhL[LIDX(lg, wr + fi * 16 + lr)];
            bf16x8 fal = AlL[LIDX(lg, wr + fi * 16 + lr)];
#pragma unroll
            for (int fj = 0; fj < 2; fj++) {
                acc[fi][fj] = __builtin_amdgcn_mfma_f32_16x16x32_bf16(fah, fbh[fj], acc[fi][fj], 0, 0, 0);
                acc[fi][fj] = __builtin_amdgcn_mfma_f32_16x16x32_bf16(fah, fbl[fj], acc[fi][fj], 0, 0, 0);
                acc[fi][fj] = __builtin_amdgcn_mfma_f32_16x16x32_bf16(fal, fbh[fj], acc[fi][fj], 0, 0, 0);
            }
        }
        __syncthreads();
    }

    const int rb = (lane >> 4) * 4;      // frag row base (C/D layout)

    if (MODE == 5) {
        // Transposed write: qkT[ln][sec][t][v*64 + cl]; float4 over reg dim.
#pragma unroll
        for (int fi = 0; fi < 4; fi++) {
            const int mb = m0 + wr + fi * 16 + rb;
            const int sec = mb >> 6, cl = mb & 63;
            float* qt = out + (size_t)ln * 3840000ull + (size_t)sec * 640000ull + cl;
            const float b0 = bias[mb], b1 = bias[mb + 1], b2 = bias[mb + 2], b3 = bias[mb + 3];
#pragma unroll
            for (int fj = 0; fj < 2; fj++) {
                const int p = p0 + wc + fj * 16 + lr;
                if (p >= PP) continue;
                const int t = p / 25, v = p - t * 25;
                f32x4 a = acc[fi][fj];
                *(float4*)(qt + (size_t)t * 1600 + v * 64) =
                    make_float4(a[0] + b0, a[1] + b1, a[2] + b2, a[3] + b3);
            }
        }
        return;
    }

    float* op = out + (OUTGLOB ? (size_t)ns : (size_t)ln) * (size_t)M * PP;
    const float* resp = nullptr;
    if (MODE == 1 || MODE == 4)
        resp = (ns < 4) ? rg0 + (size_t)ns * SAMP : rg1 + (size_t)(ns - 4) * SAMP;

#pragma unroll
    for (int fi = 0; fi < 4; fi++) {
#pragma unroll
        for (int r = 0; r < 4; r++) {
            const int m = m0 + wr + fi * 16 + rb + r;
            const float bi = (MODE == 0 || MODE == 1 || MODE == 4) ? bias[m] : 0.f;
            const float gi = (MODE == 1 || MODE == 4) ? g[m] : 0.f;
            const float be = (MODE == 1 || MODE == 4) ? beta[m] : 0.f;
            const size_t rowoff = (size_t)m * PP;
#pragma unroll
            for (int fj = 0; fj < 2; fj++) {
                const int p = p0 + wc + fj * 16 + lr;
                if (p >= PP) continue;
                const float a = acc[fi][fj][r];
                float val;
                if (MODE == 0)      val = a + bi;
                else if (MODE == 2) val = a;
                else if (MODE == 3) val = op[rowoff + p] + a;
                else if (MODE == 4) val = lrelu(resp[rowoff + p] + gi * (op[rowoff + p] + a + bi) + be);
                else                val = lrelu(resp[rowoff + p] + gi * (a + bi) + be);
                op[rowoff + p] = val;
            }
        }
    }
}

// ---------------------------------------------------------------------------
// R8/R12: temporal apply as bf16x3 MFMA. Grid (100, 4, G), one dispatch per s.
// z[ln][c][q][v] = sum_t attT[(ln*3+s)][q][t] * Y[ns][c][t][v]
// Tile 128q x 64j x 32t; K=400 padded to 416.
// ---------------------------------------------------------------------------
__global__ __launch_bounds__(256)
void apply_t_mfma(const float* __restrict__ y, const float* __restrict__ attT,
                  float* __restrict__ z, int n0, int s)
{
    const int ln = blockIdx.z;
    const int ns = n0 + ln;
    const int j0 = blockIdx.x * 64;
    const int q0 = blockIdx.y * 128;
    const float* A = attT + ((size_t)ln * 3 + s) * 160000ull;
    const float* Y = y + (size_t)ns * SAMP;
    float* zout = z + (size_t)ln * SAMP;
    const int tid = threadIdx.x;

    __shared__ __align__(16) bf16x8 AhL[512];
    __shared__ __align__(16) bf16x8 AlL[512];
    __shared__ __align__(16) bf16x8 BhL[256];
    __shared__ __align__(16) bf16x8 BlL[256];

    const int am  = tid >> 1;
    const int akb = (tid & 1) * 16;
    const int ag0 = akb >> 3;
    const int qA  = q0 + am;
    const float* arow = A + (size_t)qA * 400;

    const int bp  = tid & 63;
    const int bg_ = tid >> 6;
    const int bkg = bg_ * 8;
    const int j   = j0 + bp;                 // < 6400 always
    const int cB  = j / 25, vB = j % 25;
    const float* yrow = Y + (size_t)cB * PP + vB;   // + t*25

    const int lane = tid & 63;
    const int wv = tid >> 6;
    const int wr = (wv >> 1) * 64, wc = (wv & 1) * 32;
    const int lr = lane & 15;
    const int lg = lane >> 4;

    f32x4 acc[4][2];
#pragma unroll
    for (int i = 0; i < 4; i++)
#pragma unroll
        for (int jj = 0; jj < 2; jj++) acc[i][jj] = (f32x4){0.f, 0.f, 0.f, 0.f};

    float4 wreg[4];
    float  breg[8];

    auto loadAB = [&](int kc) {
#pragma unroll
        for (int q = 0; q < 4; q++) {
            const int ks_ = kc + akb + q * 4;
            float4 v = make_float4(0.f, 0.f, 0.f, 0.f);
            if (qA < 400 && ks_ < 400) v = ld4(arow + ks_);
            wreg[q] = v;
        }
        const int kb = kc + bkg;
#pragma unroll
        for (int i = 0; i < 8; i++) {
            const int t = kb + i;
            breg[i] = (t < 400) ? yrow[(size_t)t * 25] : 0.f;
        }
    };

    loadAB(0);

    for (int k0 = 0; k0 < 416; k0 += 32) {
        {
            bf16x8 h0, h1, l0, l1;
#pragma unroll
            for (int q = 0; q < 4; q++) {
                const float vs0 = wreg[q].x, vs1 = wreg[q].y, vs2 = wreg[q].z, vs3 = wreg[q].w;
                __bf16 hh; const int ib = q * 4;
#define CVTA(c, val) { hh = (__bf16)(val); __bf16 ll = (__bf16)((val) - (float)hh); \
    if (ib + c < 8) { h0[ib + c] = hh; l0[ib + c] = ll; } else { h1[ib + c - 8] = hh; l1[ib + c - 8] = ll; } }
                CVTA(0, vs0) CVTA(1, vs1) CVTA(2, vs2) CVTA(3, vs3)
#undef CVTA
            }
            AhL[LIDX(ag0, am)]     = h0;
            AhL[LIDX(ag0 + 1, am)] = h1;
            AlL[LIDX(ag0, am)]     = l0;
            AlL[LIDX(ag0 + 1, am)] = l1;
        }
        {
            bf16x8 hb, lb;
#pragma unroll
            for (int i = 0; i < 8; i++) {
                __bf16 hh = (__bf16)breg[i];
                hb[i] = hh;
                lb[i] = (__bf16)(breg[i] - (float)hh);
            }
            BhL[LIDXB(bg_, bp)] = hb;
            BlL[LIDXB(bg_, bp)] = lb;
        }
        __syncthreads();

        const int kn = k0 + 32;
        if (kn < 416) loadAB(kn);

        bf16x8 fbh[2], fbl[2];
#pragma unroll
        for (int fj = 0; fj < 2; fj++) {
            fbh[fj] = BhL[LIDXB(lg, wc + fj * 16 + lr)];
            fbl[fj] = BlL[LIDXB(lg, wc + fj * 16 + lr)];
        }
#pragma unroll
        for (int fi = 0; fi < 4; fi++) {
            bf16x8 fah = AhL[LIDX(lg, wr + fi * 16 + lr)];
            bf16x8 fal = AlL[LIDX(lg, wr + fi * 16 + lr)];
#pragma unroll
            for (int fj = 0; fj < 2; fj++) {
                acc[fi][fj] = __builtin_amdgcn_mfma_f32_16x16x32_bf16(fah, fbh[fj], acc[fi][fj], 0, 0, 0);
                acc[fi][fj] = __builtin_amdgcn_mfma_f32_16x16x32_bf16(fah, fbl[fj], acc[fi][fj], 0, 0, 0);
                acc[fi][fj] = __builtin_amdgcn_mfma_f32_16x16x32_bf16(fal, fbh[fj], acc[fi][fj], 0, 0, 0);
            }
        }
        __syncthreads();
    }

    const int rb = (lane >> 4) * 4;
#pragma unroll
    for (int fi = 0; fi < 4; fi++) {
#pragma unroll
        for (int r = 0; r < 4; r++) {
            const int q = q0 + wr + fi * 16 + rb + r;
            if (q >= 400) continue;
#pragma unroll
            for (int fj = 0; fj < 2; fj++) {
                const int p = j0 + wc + fj * 16 + lr;
                const int c = p / 25, v = p - c * 25;
                zout[(size_t)c * PP + (size_t)q * 25 + v] = acc[fi][fj][r];
            }
        }
    }
}

// ---------------------------------------------------------------------------
// R9/R12: temporal scores as bf16x3 MFMA with fused finalize.
// aT[idx][q][t] = tanh(sum_k Aq[q][k]*Bt[t][k] / 1600)*alphat[s] + att0t[s][t][q]
// Tile 128q x 64t x 32k, K=1600. Grid (28, 3*G): x = qtile*7 + ttile.
// ---------------------------------------------------------------------------
__global__ __launch_bounds__(256)
void scores_t_mfma(const float* __restrict__ qkT,
                   const float* __restrict__ alphat,
                   const float* __restrict__ att0t,
                   float* __restrict__ aT)
{
    const int idx = blockIdx.y;          // ln*3 + s
    const int s = idx % 3, ln = idx / 3;
    const int t0 = (blockIdx.x % 7) * 64;
    const int q0 = (blockIdx.x / 7) * 128;
    const float* base = qkT + (size_t)ln * 3840000ull;
    const float* Aq = base + (size_t)(3 + s) * 640000ull;
    const float* Bt = base + (size_t)s * 640000ull;
    const int tid = threadIdx.x;

    __shared__ __align__(16) bf16x8 AhL[512];
    __shared__ __align__(16) bf16x8 AlL[512];
    __shared__ __align__(16) bf16x8 BhL[256];
    __shared__ __align__(16) bf16x8 BlL[256];

    const int am  = tid >> 1;
    const int akb = (tid & 1) * 16;
    const int ag0 = akb >> 3;
    const int qA  = q0 + am;
    const float* arow = Aq + (size_t)qA * 1600 + akb;
    const bool aok = qA < 400;

    const int bp  = tid & 63;
    const int bg_ = tid >> 6;
    const int bkg = bg_ * 8;
    const int tB  = t0 + bp;
    const float* brow = Bt + (size_t)tB * 1600 + bkg;
    const bool bok = tB < 400;

    const int lane = tid & 63;
    const int wv = tid >> 6;
    const int wr = (wv >> 1) * 64, wc = (wv & 1) * 32;
    const int lr = lane & 15;
    const int lg = lane >> 4;

    f32x4 acc[4][2];
#pragma unroll
    for (int i = 0; i < 4; i++)
#pragma unroll
        for (int j = 0; j < 2; j++) acc[i][j] = (f32x4){0.f, 0.f, 0.f, 0.f};

    float4 areg[4];
    float4 brg[2];

    auto loadAB = [&](int kc) {
#pragma unroll
        for (int q = 0; q < 4; q++)
            areg[q] = aok ? ld4(arow + kc + q * 4) : make_float4(0.f, 0.f, 0.f, 0.f);
        brg[0] = bok ? ld4(brow + kc)     : make_float4(0.f, 0.f, 0.f, 0.f);
        brg[1] = bok ? ld4(brow + kc + 4) : make_float4(0.f, 0.f, 0.f, 0.f);
    };

    loadAB(0);

    for (int k0 = 0; k0 < 1600; k0 += 32) {
        {
            bf16x8 h0, h1, l0, l1;
#pragma unroll
            for (int q = 0; q < 4; q++) {
                const float vs0 = areg[q].x, vs1 = areg[q].y, vs2 = areg[q].z, vs3 = areg[q].w;
                __bf16 hh; const int ib = q * 4;
#define CVTA(c, val) { hh = (__bf16)(val); __bf16 ll = (__bf16)((val) - (float)hh); \
    if (ib + c < 8) { h0[ib + c] = hh; l0[ib + c] = ll; } else { h1[ib + c - 8] = hh; l1[ib + c - 8] = ll; } }
                CVTA(0, vs0) CVTA(1, vs1) CVTA(2, vs2) CVTA(3, vs3)
#undef CVTA
            }
            AhL[LIDX(ag0, am)]     = h0;
            AhL[LIDX(ag0 + 1, am)] = h1;
            AlL[LIDX(ag0, am)]     = l0;
            AlL[LIDX(ag0 + 1, am)] = l1;
        }
        {
            bf16x8 hb, lb;
#pragma unroll
            for (int e = 0; e < 2; e++) {
                const float v0 = (e ? brg[1].x : brg[0].x), v1 = (e ? brg[1].y : brg[0].y);
                const float v2 = (e ? brg[1].z : brg[0].z), v3 = (e ? brg[1].w : brg[0].w);
                __bf16 hh;
#define CVTB(c, val) { hh = (__bf16)(val); hb[e * 4 + c] = hh; lb[e * 4 + c] = (__bf16)((val) - (float)hh); }
                CVTB(0, v0) CVTB(1, v1) CVTB(2, v2) CVTB(3, v3)
#undef CVTB
            }
            BhL[LIDXB(bg_, bp)] = hb;
            BlL[LIDXB(bg_, bp)] = lb;
        }
        __syncthreads();

        const int kn = k0 + 32;
        if (kn < 1600) loadAB(kn);

        bf16x8 fbh[2], fbl[2];
#pragma unroll
        for (int fj = 0; fj < 2; fj++) {
            fbh[fj] = BhL[LIDXB(lg, wc + fj * 16 + lr)];
            fbl[fj] = BlL[LIDXB(lg, wc + fj * 16 + lr)];
        }
#pragma unroll
        for (int fi = 0; fi < 4; fi++) {
            bf16x8 fah = AhL[LIDX(lg, wr + fi * 16 + lr)];
            bf16x8 fal = AlL[LIDX(lg, wr + fi * 16 + lr)];
#pragma unroll
            for (int fj = 0; fj < 2; fj++) {
                acc[fi][fj] = __builtin_amdgcn_mfma_f32_16x16x32_bf16(fah, fbh[fj], acc[fi][fj], 0, 0, 0);
                acc[fi][fj] = __builtin_amdgcn_mfma_f32_16x16x32_bf16(fah, fbl[fj], acc[fi][fj], 0, 0, 0);
                acc[fi][fj] = __builtin_amdgcn_mfma_f32_16x16x32_bf16(fal, fbh[fj], acc[fi][fj], 0, 0, 0);
            }
        }
        __syncthreads();
    }

    const int rb = (lane >> 4) * 4;
    const float al = alphat[s];
    float* aTp = aT + (size_t)idx * 160000ull;
    const float* a0p = att0t + (size_t)s * 160000ull;

#pragma unroll
    for (int fi = 0; fi < 4; fi++) {
        const int qb = q0 + wr + fi * 16 + rb;
#pragma unroll
        for (int fj = 0; fj < 2; fj++) {
            const int t = t0 + wc + fj * 16 + lr;
            if (t >= 400) continue;
#pragma unroll
            for (int r = 0; r < 4; r++) {
                const int q = qb + r;
                if (q >= 400) continue;
                aTp[(size_t)q * 400 + t] =
                    tanhf(acc[fi][fj][r] * (1.f / 1600.f)) * al + a0p[(size_t)t * 400 + q];
            }
        }
    }
}

// ---------------------------------------------------------------------------
// Spatial scores, partial K: 200 chunks of 128 rows. Grid (200, 3, G).  [R0]
// ---------------------------------------------------------------------------
__global__ __launch_bounds__(256)
void scores_s_partial(const float* __restrict__ qk, float* __restrict__ part)
{
    const int chunk = blockIdx.x, s = blockIdx.y, ln = blockIdx.z;
    const float* qsec = qk + ((size_t)ln * 384 + s * 64) * PP + (size_t)chunk * 3200;
    const float* ksec = qk + ((size_t)ln * 384 + (3 + s) * 64) * PP + (size_t)chunk * 3200;
    __shared__ float QL[3200];
    __shared__ float KL[3200];
    const int tid = threadIdx.x;
    for (int i = tid; i < 3200; i += 256) {
        QL[i] = qsec[i];
        KL[i] = ksec[i];
    }
    __syncthreads();
    const int o0 = tid, o1 = tid + 256, o2 = tid + 512;
    const int u0 = o0 / 25, v0 = o0 % 25;
    const int u1 = o1 / 25, v1 = o1 % 25;
    const int u2 = o2 / 25, v2 = o2 % 25;
    float a0 = 0.f, a1 = 0.f, a2 = 0.f;
#pragma unroll 8
    for (int r = 0; r < 128; r++) {
        int ro = r * 25;
        a0 = fmaf(QL[ro + u0], KL[ro + v0], a0);
        a1 = fmaf(QL[ro + u1], KL[ro + v1], a1);
        if (tid < 113) a2 = fmaf(QL[ro + u2], KL[ro + v2], a2);
    }
    float* pp = part + (((size_t)(ln * 3 + s)) * 200 + chunk) * 625;
    pp[o0] = a0;
    pp[o1] = a1;
    if (tid < 113) pp[o2] = a2;
}

// grid.x = 3*G blocks (idx = ln*3+s), 640 threads. Sums 200 partials.  [R0]
__global__ void scores_s_final(const float* __restrict__ part,
                               const float* __restrict__ alphas,
                               const float* __restrict__ att0s,
                               float* __restrict__ atts)
{
    const int idx = blockIdx.x;
    const int s = idx % 3;
    const int o = threadIdx.x;
    if (o >= 625) return;
    const float* pb = part + (size_t)idx * 200 * 625 + o;
    float sum = 0.f;
#pragma unroll 8
    for (int i = 0; i < 200; i++) sum += pb[(size_t)i * 625];
    atts[(size_t)idx * 625 + o] = tanhf(sum * (1.f / 25600.f)) * alphas[s] + att0s[s * 625 + o];
}

// ---------------------------------------------------------------------------
// Spatial apply (one s). Grid (200, G).  [R0]
// ---------------------------------------------------------------------------
__global__ __launch_bounds__(256)
void apply_s_kernel(const float* __restrict__ x0, const float* __restrict__ x1,
                    const float* __restrict__ atts, float* __restrict__ z,
                    int n0, int s)
{
    const int ln = blockIdx.y;
    const int ns = n0 + ln;
    const int tid = threadIdx.x;
    __shared__ float attL[700];   // 25*28 padded
    for (int i = tid; i < 700; i += 256) attL[i] = 0.f;
    __syncthreads();
    for (int i = tid; i < 625; i += 256) {
        int v = i / 25, w = i % 25;
        attL[v * 28 + w] = atts[(size_t)ln * 1875 + s * 625 + i];
    }
    __syncthreads();
    const float* xp = (ns < 4) ? x0 + (size_t)ns * SAMP : x1 + (size_t)(ns - 4) * SAMP;
    const int r0 = (blockIdx.x * 256 + tid) * 2;   // even; both rows share c
    const float* xr0 = xp + (size_t)r0 * 25;
    float xr[2][25];
#pragma unroll
    for (int i = 0; i < 2; i++)
#pragma unroll
        for (int v = 0; v < 25; v++) xr[i][v] = xr0[i * 25 + v];
    const int c0 = r0 / 400, t0 = r0 % 400;

    float4 acc0[7], acc1[7];
#pragma unroll
    for (int w4 = 0; w4 < 7; w4++) {
        acc0[w4] = make_float4(0.f, 0.f, 0.f, 0.f);
        acc1[w4] = make_float4(0.f, 0.f, 0.f, 0.f);
    }
#pragma unroll
    for (int v = 0; v < 25; v++) {
        const float4* arow = (const float4*)&attL[v * 28];
        float xv0 = xr[0][v], xv1 = xr[1][v];
#pragma unroll
        for (int w4 = 0; w4 < 7; w4++) {
            float4 a = arow[w4];
            acc0[w4].x = fmaf(xv0, a.x, acc0[w4].x);
            acc0[w4].y = fmaf(xv0, a.y, acc0[w4].y);
            acc0[w4].z = fmaf(xv0, a.z, acc0[w4].z);
            acc0[w4].w = fmaf(xv0, a.w, acc0[w4].w);
            acc1[w4].x = fmaf(xv1, a.x, acc1[w4].x);
            acc1[w4].y = fmaf(xv1, a.y, acc1[w4].y);
            acc1[w4].z = fmaf(xv1, a.z, acc1[w4].z);
            acc1[w4].w = fmaf(xv1, a.w, acc1[w4].w);
        }
    }
    float* zp = z + (size_t)ln * SAMP + (size_t)c0 * PP + (size_t)t0 * 25;
#pragma unroll
    for (int w4 = 0; w4 < 7; w4++) {
        int wb = w4 * 4;
        if (wb + 0 < 25) zp[wb + 0] = acc0[w4].x;
        if (wb + 1 < 25) zp[wb + 1] = acc0[w4].y;
        if (wb + 2 < 25) zp[wb + 2] = acc0[w4].z;
        if (wb + 3 < 25) zp[wb + 3] = acc0[w4].w;
    }
#pragma unroll
    for (int w4 = 0; w4 < 7; w4++) {
        int wb = w4 * 4;
        if (wb + 0 < 25) zp[25 + wb + 0] = acc1[w4].x;
        if (wb + 1 < 25) zp[25 + wb + 1] = acc1[w4].y;
        if (wb + 2 < 25) zp[25 + wb + 2] = acc1[w4].z;
        if (wb + 3 < 25) zp[25 + wb + 3] = acc1[w4].w;
    }
}

// ---------------------------------------------------------------------------
extern "C" void kernel_launch(void* const* d_in, const int* in_sizes, int n_in,
                              void* d_out, int out_size, void* d_ws, size_t ws_size,
                              hipStream_t stream)
{
    const float* x    = (const float*)d_in[0];
    const float* x1   = (const float*)d_in[1];
    const float* pe_s = (const float*)d_in[2];
    const float* pe_t = (const float*)d_in[3];
    const float* Wsi  = (const float*)d_in[4];
    const float* bsi  = (const float*)d_in[5];
    const float* alphas = (const float*)d_in[6];
    const float* att0s  = (const float*)d_in[7];
    const float* Wso  = (const float*)d_in[8];
    const float* bso  = (const float*)d_in[9];
    const float* gso  = (const float*)d_in[10];
    const float* beso = (const float*)d_in[11];
    const float* Wsf  = (const float*)d_in[12];
    const float* bsf  = (const float*)d_in[13];
    const float* gsf  = (const float*)d_in[14];
    const float* besf = (const float*)d_in[15];
    const float* Wti  = (const float*)d_in[16];
    const float* bti  = (const float*)d_in[17];
    const float* alphat = (const float*)d_in[18];
    const float* att0t  = (const float*)d_in[19];
    const float* Wto  = (const float*)d_in[20];
    const float* bto  = (const float*)d_in[21];
    const float* gto  = (const float*)d_in[22];
    const float* beto = (const float*)d_in[23];
    const float* Wtf  = (const float*)d_in[24];
    const float* btf  = (const float*)d_in[25];
    const float* gtf  = (const float*)d_in[26];
    const float* betf = (const float*)d_in[27];

    float* outp = (float*)d_out;
    const float* outpB = outp + 4ull * SAMP;   // samples 4..7 view

    int G = 1;
    for (int g = 8; g >= 1; g >>= 1) {
        if ((size_t)g * 27587500ull <= ws_size) { G = g; break; }
    }

    float* A   = (float*)d_ws;                       // qk / qkT, then h overlay
    float* Zs  = A  + (size_t)G * 3840000ull;        // z slice / score partials
    float* aT  = Zs + (size_t)G * 2560000ull;        // temporal att
    float* sp  = aT + (size_t)G * 480000ull;         // (unused, kept for layout)
    float* as  = sp + (size_t)G * 15000ull;          // spatial att

    dim3 blk(256);
    for (int n0 = 0; n0 < 8; n0 += G) {
        dim3 gIn(157, 3, G), gOut(157, 2, G);        // x = p-tile (64 wide)

        // ---- spatial stage (input x / x1) ----
        gemm_mfma<0, true, true, false><<<gIn, blk, 0, stream>>>(
            Wsi, 256, bsi, nullptr, nullptr, x, x1, nullptr, pe_s,
            nullptr, nullptr, A, n0, 384, 256);
        scores_s_partial<<<dim3(200, 3, G), blk, 0, stream>>>(A, Zs);
        scores_s_final<<<dim3(3 * G), dim3(640), 0, stream>>>(Zs, alphas, att0s, as);
        for (int s = 0; s < 3; s++) {
            apply_s_kernel<<<dim3(200, G), blk, 0, stream>>>(x, x1, as, Zs, n0, s);
            if (s == 0)
                gemm_mfma<2, false, false, false><<<gOut, blk, 0, stream>>>(
                    Wso + s * 256, 768, nullptr, nullptr, nullptr, nullptr, nullptr, Zs,
                    nullptr, nullptr, nullptr, A, n0, 256, 256);
            else if (s == 1)
                gemm_mfma<3, false, false, false><<<gOut, blk, 0, stream>>>(
                    Wso + s * 256, 768, nullptr, nullptr, nullptr, nullptr, nullptr, Zs,
                    nullptr, nullptr, nullptr, A, n0, 256, 256);
            else
                gemm_mfma<4, false, false, false><<<gOut, blk, 0, stream>>>(
                    Wso + s * 256, 768, bso, gso, beso, nullptr, nullptr, Zs,
                    nullptr, x, x1, A, n0, 256, 256);
        }
        gemm_mfma<1, false, false, true><<<gOut, blk, 0, stream>>>(
            Wsf, 256, bsf, gsf, besf, nullptr, nullptr, A, nullptr,
            x, x1, outp, n0, 256, 256);

        // ---- temporal stage (input d_out, in place) ----
        gemm_mfma<5, true, true, false><<<gIn, blk, 0, stream>>>(
            Wti, 256, bti, nullptr, nullptr, outp, outpB, nullptr, pe_t,
            nullptr, nullptr, A, n0, 384, 256);
        scores_t_mfma<<<dim3(28, 3 * G), blk, 0, stream>>>(A, alphat, att0t, aT);
        for (int s = 0; s < 3; s++) {
            apply_t_mfma<<<dim3(100, 4, G), blk, 0, stream>>>(outp, aT, Zs, n0, s);
            if (s == 0)
                gemm_mfma<2, false, false, false><<<gOut, blk, 0, stream>>>(
                    Wto + s * 256, 768, nullptr, nullptr, nullptr, nullptr, nullptr, Zs,
                    nullptr, nullptr, nullptr, A, n0, 256, 256);
            else if (s == 1)
                gemm_mfma<3, false, false, false><<<gOut, blk, 0, stream>>>(
                    Wto + s * 256, 768, nullptr, nullptr, nullptr, nullptr, nullptr, Zs,
                    nullptr, nullptr, nullptr, A, n0, 256, 256);
            else
                gemm_mfma<4, false, false, false><<<gOut, blk, 0, stream>>>(
                    Wto + s * 256, 768, bto, gto, beto, nullptr, nullptr, Zs,
                    nullptr, outp, outpB, A, n0, 256, 256);
        }
        gemm_mfma<1, false, false, true><<<gOut, blk, 0, stream>>>(
            Wtf, 256, btf, gtf, betf, nullptr, nullptr, A, nullptr,
            outp, outpB, outp, n0, 256, 256);
    }
}